// Round 1
// baseline (312.443 us; speedup 1.0000x reference)
//
#include <hip/hip_runtime.h>
#include <hip/hip_bf16.h>

#define B_ 32
#define L_ 1024
#define D_ 1024
#define E_ 100
#define E1_ 101
#define M2_ (B_ * E1_)   // 3232 entity rows (incl. none-entity)
#define NP_ 1028         // padded ent_proj row stride (1025 -> 1028 for float4 alignment)
#define QBLK_ 32         // rows per scores block
#define NBLK3_ 7         // ceil(Q_MAX=200 / 32)
#define FC_ 64           // f-chunk for scores kernel

// ---------------- K1: encoded_entity[b,e,:] = sum of q_enc rows (r0+1 .. r1-1); e==E -> none_entity
__global__ __launch_bounds__(256) void k_encode(const float* __restrict__ q_enc,
                                                const float* __restrict__ none_ent,
                                                const int* __restrict__ ranges,
                                                float* __restrict__ enc) {
    int be = blockIdx.x;            // 0..M2_-1
    int b = be / E1_, e = be % E1_;
    int t = threadIdx.x;            // 256 threads * float4 = 1024 cols
    float4 acc = make_float4(0.f, 0.f, 0.f, 0.f);
    if (e == E_) {
        acc = *(const float4*)&none_ent[t * 4];
    } else {
        int r0 = ranges[(b * E_ + e) * 2 + 0];
        int r1 = ranges[(b * E_ + e) * 2 + 1];
        for (int l = r0 + 1; l < r1; ++l) {
            float4 v = *(const float4*)&q_enc[((size_t)b * L_ + l) * D_ + t * 4];
            acc.x += v.x; acc.y += v.y; acc.z += v.z; acc.w += v.w;
        }
    }
    *(float4*)&enc[(size_t)be * D_ + t * 4] = acc;
}

// ---------------- K2: ent_proj[M2][1025(->NP)] = enc[M2][1024] @ W^T + bias
// fp32 tiled GEMM, NT layout (both K-contiguous). BM=BN=64, BK=16, 4x4 per thread.
__global__ __launch_bounds__(256) void k_entproj(const float* __restrict__ A,
                                                 const float* __restrict__ W,
                                                 const float* __restrict__ bias,
                                                 float* __restrict__ C) {
    __shared__ float As[16][68];   // transposed: As[k][m], pad 68 (aligned float4, 2-way max)
    __shared__ float Bs[16][68];
    int tid = threadIdx.x;
    int tx = tid & 15, ty = tid >> 4;
    int m0 = blockIdx.y * 64, n0 = blockIdx.x * 64;
    int lr = tid >> 2;             // 0..63 tile row
    int lk = (tid & 3) * 4;        // 0,4,8,12
    float acc[4][4] = {};
    for (int k0 = 0; k0 < 1024; k0 += 16) {
        float4 av = make_float4(0.f, 0.f, 0.f, 0.f);
        int gm = m0 + lr;
        if (gm < M2_) av = *(const float4*)&A[(size_t)gm * 1024 + k0 + lk];
        As[lk + 0][lr] = av.x; As[lk + 1][lr] = av.y;
        As[lk + 2][lr] = av.z; As[lk + 3][lr] = av.w;
        float4 bv = make_float4(0.f, 0.f, 0.f, 0.f);
        int gn = n0 + lr;
        if (gn < 1025) bv = *(const float4*)&W[(size_t)gn * 1024 + k0 + lk];
        Bs[lk + 0][lr] = bv.x; Bs[lk + 1][lr] = bv.y;
        Bs[lk + 2][lr] = bv.z; Bs[lk + 3][lr] = bv.w;
        __syncthreads();
        #pragma unroll
        for (int kk = 0; kk < 16; ++kk) {
            float4 a  = *(const float4*)&As[kk][ty * 4];
            float4 bb = *(const float4*)&Bs[kk][tx * 4];
            acc[0][0] += a.x * bb.x; acc[0][1] += a.x * bb.y; acc[0][2] += a.x * bb.z; acc[0][3] += a.x * bb.w;
            acc[1][0] += a.y * bb.x; acc[1][1] += a.y * bb.y; acc[1][2] += a.y * bb.z; acc[1][3] += a.y * bb.w;
            acc[2][0] += a.z * bb.x; acc[2][1] += a.z * bb.y; acc[2][2] += a.z * bb.z; acc[2][3] += a.z * bb.w;
            acc[3][0] += a.w * bb.x; acc[3][1] += a.w * bb.y; acc[3][2] += a.w * bb.z; acc[3][3] += a.w * bb.w;
        }
        __syncthreads();
    }
    #pragma unroll
    for (int i = 0; i < 4; ++i) {
        int gm = m0 + ty * 4 + i;
        if (gm >= M2_) continue;
        #pragma unroll
        for (int j = 0; j < 4; ++j) {
            int gn = n0 + tx * 4 + j;
            if (gn < 1025) C[(size_t)gm * NP_ + gn] = acc[i][j] + bias[gn];
        }
    }
}

// ---------------- K3: per (b, 32-row tile): scores -> softmax -> co_att rows + partial att sums
// threads: 256 = 32 rows (tid&31) x 8 entity-groups (tid>>5); entity e = eg + 8*j, j=0..12
__global__ __launch_bounds__(256) void k_scores(const float* __restrict__ q_enc,
                                                const float* __restrict__ hint,
                                                const float* __restrict__ ep,
                                                const int* __restrict__ qlen,
                                                float* __restrict__ co_att,
                                                float* __restrict__ partial) {
    __shared__ float Aq[FC_][33];    // transposed q_enc chunk: Aq[k][l] (conflict-free reads)
    __shared__ float Ep[E1_][FC_];   // ent_proj chunk (broadcast reads)
    __shared__ float red[QBLK_][8];
    int b = blockIdx.y;
    int l0 = blockIdx.x * QBLK_;
    int tid = threadIdx.x;
    int l = tid & 31, eg = tid >> 5;
    int qn = qlen[b];
    if (l0 >= qn) {  // uniform branch: whole tile masked -> zero partials
        for (int e = tid; e < E1_; e += 256)
            partial[((size_t)b * NBLK3_ + blockIdx.x) * E1_ + e] = 0.f;
        return;
    }
    float acc[13];
    #pragma unroll
    for (int j = 0; j < 13; ++j) acc[j] = 0.f;

    for (int f0 = 0; f0 < 1024; f0 += FC_) {
        for (int idx = tid; idx < QBLK_ * (FC_ / 4); idx += 256) {
            int lr = idx / (FC_ / 4), c4 = (idx % (FC_ / 4)) * 4;
            float4 v = *(const float4*)&q_enc[((size_t)b * L_ + l0 + lr) * D_ + f0 + c4];
            Aq[c4 + 0][lr] = v.x; Aq[c4 + 1][lr] = v.y;
            Aq[c4 + 2][lr] = v.z; Aq[c4 + 3][lr] = v.w;
        }
        for (int idx = tid; idx < E1_ * (FC_ / 4); idx += 256) {
            int er = idx / (FC_ / 4), c4 = (idx % (FC_ / 4)) * 4;
            *(float4*)&Ep[er][c4] = *(const float4*)&ep[((size_t)b * E1_ + er) * NP_ + f0 + c4];
        }
        __syncthreads();
        for (int kk = 0; kk < FC_; kk += 4) {
            float a0 = Aq[kk + 0][l], a1 = Aq[kk + 1][l];
            float a2 = Aq[kk + 2][l], a3 = Aq[kk + 3][l];
            #pragma unroll
            for (int j = 0; j < 13; ++j) {
                int e = eg + 8 * j;
                if (e < E1_) {
                    float4 ev = *(const float4*)&Ep[e][kk];
                    acc[j] += a0 * ev.x + a1 * ev.y + a2 * ev.z + a3 * ev.w;
                }
            }
        }
        __syncthreads();
    }
    // hint feature (f = 1024)
    float h = hint[(size_t)b * L_ + l0 + l];
    #pragma unroll
    for (int j = 0; j < 13; ++j) {
        int e = eg + 8 * j;
        if (e < E1_) acc[j] += h * ep[((size_t)b * E1_ + e) * NP_ + 1024];
    }
    // ---- softmax over the 101 entities of row l (spread across 8 egs)
    float mloc = -3.4e38f;
    #pragma unroll
    for (int j = 0; j < 13; ++j) if (eg + 8 * j < E1_) mloc = fmaxf(mloc, acc[j]);
    red[l][eg] = mloc;
    __syncthreads();
    float m = red[l][0];
    #pragma unroll
    for (int k = 1; k < 8; ++k) m = fmaxf(m, red[l][k]);
    __syncthreads();
    float p[13];
    #pragma unroll
    for (int j = 0; j < 13; ++j) p[j] = 0.f;
    float sloc = 0.f;
    #pragma unroll
    for (int j = 0; j < 13; ++j) {
        if (eg + 8 * j < E1_) { p[j] = __expf(acc[j] - m); sloc += p[j]; }
    }
    red[l][eg] = sloc;
    __syncthreads();
    float s = 0.f;
    #pragma unroll
    for (int k = 0; k < 8; ++k) s += red[l][k];
    float inv = 1.f / s;
    bool valid = (l0 + l) < qn;
    if (valid) {
        float* row = &co_att[((size_t)b * L_ + l0 + l) * E1_];
        #pragma unroll
        for (int j = 0; j < 13; ++j) {
            int e = eg + 8 * j;
            if (e < E1_) row[e] = p[j] * inv;
        }
    }
    // ---- partial att: sum over this block's valid rows (reduce over l within half-wave)
    float mask = valid ? inv : 0.f;
    #pragma unroll
    for (int j = 0; j < 13; ++j) {
        int e = eg + 8 * j;
        float v = (e < E1_) ? p[j] * mask : 0.f;
        v += __shfl_xor(v, 1);  v += __shfl_xor(v, 2);
        v += __shfl_xor(v, 4);  v += __shfl_xor(v, 8);
        v += __shfl_xor(v, 16);
        if ((tid & 31) == 0 && e < E1_)
            partial[((size_t)b * NBLK3_ + blockIdx.x) * E1_ + e] = v;
    }
}

// ---------------- K4: att[b,e] = min(sum of partials, 1)
__global__ __launch_bounds__(256) void k_final(const float* __restrict__ partial,
                                               float* __restrict__ att) {
    int i = blockIdx.x * 256 + threadIdx.x;
    if (i >= B_ * E_) return;
    int b = i / E_, e = i % E_;
    float s = 0.f;
    #pragma unroll
    for (int k = 0; k < NBLK3_; ++k) s += partial[((size_t)b * NBLK3_ + k) * E1_ + e];
    att[i] = fminf(s, 1.f);
}

extern "C" void kernel_launch(void* const* d_in, const int* in_sizes, int n_in,
                              void* d_out, int out_size, void* d_ws, size_t ws_size,
                              hipStream_t stream) {
    const float* q_enc    = (const float*)d_in[0];
    const float* hint     = (const float*)d_in[1];
    const float* W        = (const float*)d_in[2];
    const float* bias     = (const float*)d_in[3];
    const float* none_ent = (const float*)d_in[4];
    const int*   qlen     = (const int*)d_in[5];
    const int*   ranges   = (const int*)d_in[6];

    float* att    = (float*)d_out;                 // [B, E]
    float* co_att = att + (size_t)B_ * E_;         // [B, L, E1]

    float* enc  = (float*)d_ws;                    // [M2, D]
    float* ep   = enc + (size_t)M2_ * D_;          // [M2, NP]
    float* part = ep + (size_t)M2_ * NP_;          // [B, NBLK3, E1]

    // zero the co_att region (rows >= q_q_len must be exactly 0; replays start from 0xAA poison)
    hipMemsetAsync(co_att, 0, (size_t)B_ * L_ * E1_ * sizeof(float), stream);

    k_encode<<<M2_, 256, 0, stream>>>(q_enc, none_ent, ranges, enc);
    k_entproj<<<dim3(17, 51), 256, 0, stream>>>(enc, W, bias, ep);
    k_scores<<<dim3(NBLK3_, B_), 256, 0, stream>>>(q_enc, hint, ep, qlen, co_att, part);
    k_final<<<13, 256, 0, stream>>>(part, att);
}

// Round 2
// 106.904 us; speedup vs baseline: 2.9227x; 2.9227x over previous
//
#include <hip/hip_runtime.h>
#include <hip/hip_bf16.h>

typedef unsigned short u16;
typedef __attribute__((ext_vector_type(8))) short short8;
typedef __attribute__((ext_vector_type(4))) float f32x4;

#define B_ 32
#define L_ 1024
#define D_ 1024
#define E_ 100
#define E1_ 101
#define M2_ (B_ * E1_)     // 3232 entity rows (incl. none-entity)
#define M2P_ 3264          // padded to 51*64 for MFMA tiles
#define QBLK_ 32
#define NBLK3_ 7

#define MFMA16(a, b, c) __builtin_amdgcn_mfma_f32_16x16x32_bf16((a), (b), (c), 0, 0, 0)

__device__ __forceinline__ void split2(float x, u16& h, u16& l) {
    __hip_bfloat16 bh = __float2bfloat16(x);          // RN
    float r = x - __bfloat162float(bh);
    __hip_bfloat16 bl = __float2bfloat16(r);
    h = __builtin_bit_cast(u16, bh);
    l = __builtin_bit_cast(u16, bl);
}

// ---------------- K1: segment-sum -> enc hi/lo bf16 split; fused last column
// ep_last[be] = dot(enc_row, W[1024,:]) + bias[1024]
__global__ __launch_bounds__(256) void k_encode(const float* __restrict__ q_enc,
                                                const float* __restrict__ none_ent,
                                                const float* __restrict__ W,
                                                const float* __restrict__ bias,
                                                const int* __restrict__ ranges,
                                                u16* __restrict__ enc_hi, u16* __restrict__ enc_lo,
                                                float* __restrict__ ep_last) {
    __shared__ float red4[4];
    int be = blockIdx.x;
    int b = be / E1_, e = be - b * E1_;
    int t = threadIdx.x, c = t * 4;
    float4 acc;
    if (e == E_) {
        acc = *(const float4*)&none_ent[c];
    } else {
        acc = make_float4(0.f, 0.f, 0.f, 0.f);
        int r0 = ranges[(b * E_ + e) * 2 + 0];
        int r1 = ranges[(b * E_ + e) * 2 + 1];
        for (int l = r0 + 1; l < r1; ++l) {
            float4 v = *(const float4*)&q_enc[((size_t)b * L_ + l) * D_ + c];
            acc.x += v.x; acc.y += v.y; acc.z += v.z; acc.w += v.w;
        }
    }
    union { u16 u[4]; float2 f; } ph, pl;
    split2(acc.x, ph.u[0], pl.u[0]); split2(acc.y, ph.u[1], pl.u[1]);
    split2(acc.z, ph.u[2], pl.u[2]); split2(acc.w, ph.u[3], pl.u[3]);
    *(float2*)&enc_hi[(size_t)be * 1024 + c] = ph.f;
    *(float2*)&enc_lo[(size_t)be * 1024 + c] = pl.f;
    // fused last column (hint-weight row of W)
    const float* w1k = W + (size_t)1024 * 1024;
    float4 wv = *(const float4*)&w1k[c];
    float s = acc.x * wv.x + acc.y * wv.y + acc.z * wv.z + acc.w * wv.w;
    #pragma unroll
    for (int off = 32; off; off >>= 1) s += __shfl_down(s, off);
    if ((t & 63) == 0) red4[t >> 6] = s;
    __syncthreads();
    if (t == 0) ep_last[be] = red4[0] + red4[1] + red4[2] + red4[3] + bias[1024];
}

// ---------------- K2: W rows 0..1023 -> bf16 hi/lo
__global__ __launch_bounds__(256) void k_wsplit(const float* __restrict__ W,
                                                u16* __restrict__ w_hi, u16* __restrict__ w_lo) {
    int r = blockIdx.x, c = threadIdx.x * 4;
    float4 v = *(const float4*)&W[(size_t)r * 1024 + c];
    union { u16 u[4]; float2 f; } ph, pl;
    split2(v.x, ph.u[0], pl.u[0]); split2(v.y, ph.u[1], pl.u[1]);
    split2(v.z, ph.u[2], pl.u[2]); split2(v.w, ph.u[3], pl.u[3]);
    *(float2*)&w_hi[(size_t)r * 1024 + c] = ph.f;
    *(float2*)&w_lo[(size_t)r * 1024 + c] = pl.f;
}

// ---------------- K3: ep[m][n] = enc[m][:] . W[n][:] + bias[n], 3-term bf16 MFMA
// 64x64 tile, BK=64, 4 waves (2x2), wave = 32x32 = 2x2 frags of 16x16x32.
__global__ __launch_bounds__(256) void k_entproj(const u16* __restrict__ A_hi, const u16* __restrict__ A_lo,
                                                 const u16* __restrict__ B_hi, const u16* __restrict__ B_lo,
                                                 const float* __restrict__ bias,
                                                 u16* __restrict__ ep_hi, u16* __restrict__ ep_lo) {
    __shared__ __attribute__((aligned(16))) u16 Ah[64 * 64], Al[64 * 64], Bh[64 * 64], Bl[64 * 64];
    int tid = threadIdx.x;
    int m0 = blockIdx.y * 64, n0 = blockIdx.x * 64;
    int w = tid >> 6, lane = tid & 63, lr = lane & 15, lg = lane >> 4;
    int wr = w >> 1, wc = w & 1;
    f32x4 zero = {0.f, 0.f, 0.f, 0.f};
    f32x4 acc[2][2] = {{zero, zero}, {zero, zero}};
    for (int k0 = 0; k0 < 1024; k0 += 64) {
        #pragma unroll
        for (int p = 0; p < 2; ++p) {
            int i = p * 256 + tid, r = i >> 3, s = i & 7;
            int dst = r * 64 + ((s ^ (r & 7)) << 3);
            size_t ga = (size_t)(m0 + r) * 1024 + k0 + s * 8;
            size_t gb = (size_t)(n0 + r) * 1024 + k0 + s * 8;
            *(float4*)&Ah[dst] = *(const float4*)&A_hi[ga];
            *(float4*)&Al[dst] = *(const float4*)&A_lo[ga];
            *(float4*)&Bh[dst] = *(const float4*)&B_hi[gb];
            *(float4*)&Bl[dst] = *(const float4*)&B_lo[gb];
        }
        __syncthreads();
        #pragma unroll
        for (int ks = 0; ks < 64; ks += 32) {
            int sk = (ks >> 3) + lg;
            short8 ah[2], al[2], bh[2], bl[2];
            #pragma unroll
            for (int mf = 0; mf < 2; ++mf) {
                int r = wr * 32 + mf * 16 + lr;
                int ad = r * 64 + ((sk ^ (r & 7)) << 3);
                ah[mf] = __builtin_bit_cast(short8, *(const float4*)&Ah[ad]);
                al[mf] = __builtin_bit_cast(short8, *(const float4*)&Al[ad]);
            }
            #pragma unroll
            for (int nf = 0; nf < 2; ++nf) {
                int r = wc * 32 + nf * 16 + lr;
                int ad = r * 64 + ((sk ^ (r & 7)) << 3);
                bh[nf] = __builtin_bit_cast(short8, *(const float4*)&Bh[ad]);
                bl[nf] = __builtin_bit_cast(short8, *(const float4*)&Bl[ad]);
            }
            #pragma unroll
            for (int mf = 0; mf < 2; ++mf)
                #pragma unroll
                for (int nf = 0; nf < 2; ++nf) {
                    acc[mf][nf] = MFMA16(ah[mf], bh[nf], acc[mf][nf]);
                    acc[mf][nf] = MFMA16(ah[mf], bl[nf], acc[mf][nf]);
                    acc[mf][nf] = MFMA16(al[mf], bh[nf], acc[mf][nf]);
                }
        }
        __syncthreads();
    }
    #pragma unroll
    for (int mf = 0; mf < 2; ++mf)
        #pragma unroll
        for (int nf = 0; nf < 2; ++nf)
            #pragma unroll
            for (int reg = 0; reg < 4; ++reg) {
                int m = m0 + wr * 32 + mf * 16 + lg * 4 + reg;
                if (m < M2_) {
                    int n = n0 + wc * 32 + nf * 16 + lr;
                    float v = acc[mf][nf][reg] + bias[n];
                    u16 h, l;
                    split2(v, h, l);
                    ep_hi[(size_t)m * 1024 + n] = h;
                    ep_lo[(size_t)m * 1024 + n] = l;
                }
            }
}

// ---------------- K4: scores (MFMA, A=q rows split on the fly, B=ep rows) + fused softmax
// block = (b, 32-row tile). N padded to 112 (7 frags). 4 waves: mf=w&1, nfrags {0..3}/{4..6}.
__global__ __launch_bounds__(256) void k_scores(const float* __restrict__ q_enc,
                                                const float* __restrict__ hint,
                                                const u16* __restrict__ ep_hi, const u16* __restrict__ ep_lo,
                                                const float* __restrict__ ep_last,
                                                const int* __restrict__ qlen,
                                                float* __restrict__ co_att,
                                                float* __restrict__ partial) {
    __shared__ __attribute__((aligned(16))) u16 Ah[32 * 64], Al[32 * 64], Bh[112 * 64], Bl[112 * 64];
    __shared__ float Ss[32 * 113];
    __shared__ float red[QBLK_][8];
    int b = blockIdx.y, mt = blockIdx.x, l0 = mt * QBLK_;
    int tid = threadIdx.x;
    int qn = qlen[b];
    if (l0 >= qn) {
        for (int e = tid; e < E1_; e += 256)
            partial[((size_t)b * NBLK3_ + mt) * E1_ + e] = 0.f;
        return;
    }
    int w = tid >> 6, lane = tid & 63, lr = lane & 15, lg = lane >> 4;
    int mf = w & 1, nb = (w >> 1) * 4, nc = (w >> 1) ? 3 : 4;
    f32x4 zero = {0.f, 0.f, 0.f, 0.f};
    f32x4 acc[4] = {zero, zero, zero, zero};
    for (int k0 = 0; k0 < 1024; k0 += 64) {
        {   // A: 32 rows x 64 k, split fp32 -> hi/lo on the fly (1 slot per thread)
            int r = tid >> 3, s = tid & 7;
            const float* src = &q_enc[((size_t)b * L_ + l0 + r) * D_ + k0 + s * 8];
            float4 x0 = *(const float4*)src, x1 = *(const float4*)(src + 4);
            float xs[8] = {x0.x, x0.y, x0.z, x0.w, x1.x, x1.y, x1.z, x1.w};
            short8 hv, lv;
            #pragma unroll
            for (int j = 0; j < 8; ++j) {
                u16 hh, ll;
                split2(xs[j], hh, ll);
                hv[j] = (short)hh; lv[j] = (short)ll;
            }
            int dst = r * 64 + ((s ^ (r & 7)) << 3);
            *(float4*)&Ah[dst] = __builtin_bit_cast(float4, hv);
            *(float4*)&Al[dst] = __builtin_bit_cast(float4, lv);
        }
        for (int i = tid; i < 112 * 8; i += 256) {  // B: ep rows (over-read past e=100, finite garbage)
            int r = i >> 3, s = i & 7;
            size_t g = ((size_t)b * E1_ + r) * 1024 + k0 + s * 8;
            int dst = r * 64 + ((s ^ (r & 7)) << 3);
            *(float4*)&Bh[dst] = *(const float4*)&ep_hi[g];
            *(float4*)&Bl[dst] = *(const float4*)&ep_lo[g];
        }
        __syncthreads();
        #pragma unroll
        for (int ks = 0; ks < 64; ks += 32) {
            int sk = (ks >> 3) + lg;
            int rA = mf * 16 + lr;
            int adA = rA * 64 + ((sk ^ (rA & 7)) << 3);
            short8 ah = __builtin_bit_cast(short8, *(const float4*)&Ah[adA]);
            short8 al = __builtin_bit_cast(short8, *(const float4*)&Al[adA]);
            #pragma unroll
            for (int nf = 0; nf < 4; ++nf) {
                if (nf < nc) {
                    int rB = (nb + nf) * 16 + lr;
                    int adB = rB * 64 + ((sk ^ (rB & 7)) << 3);
                    short8 bh = __builtin_bit_cast(short8, *(const float4*)&Bh[adB]);
                    short8 bl = __builtin_bit_cast(short8, *(const float4*)&Bl[adB]);
                    acc[nf] = MFMA16(ah, bh, acc[nf]);
                    acc[nf] = MFMA16(ah, bl, acc[nf]);
                    acc[nf] = MFMA16(al, bh, acc[nf]);
                }
            }
        }
        __syncthreads();
    }
    // dump score frags to LDS: row = mf*16 + lg*4 + reg, col = (nb+nf)*16 + lr
    #pragma unroll
    for (int nf = 0; nf < 4; ++nf)
        if (nf < nc) {
            #pragma unroll
            for (int reg = 0; reg < 4; ++reg)
                Ss[(mf * 16 + lg * 4 + reg) * 113 + (nb + nf) * 16 + lr] = acc[nf][reg];
        }
    __syncthreads();
    // ---- softmax over 101 entities per row
    int l = tid & 31, eg = tid >> 5;
    float h = hint[(size_t)b * L_ + l0 + l];
    float sc[13];
    #pragma unroll
    for (int j = 0; j < 13; ++j) {
        int e = eg + 8 * j;
        sc[j] = (e < E1_) ? (Ss[l * 113 + e] + h * ep_last[b * E1_ + e]) : -3.4e38f;
    }
    float mloc = -3.4e38f;
    #pragma unroll
    for (int j = 0; j < 13; ++j) mloc = fmaxf(mloc, sc[j]);
    red[l][eg] = mloc;
    __syncthreads();
    float m = red[l][0];
    #pragma unroll
    for (int k = 1; k < 8; ++k) m = fmaxf(m, red[l][k]);
    __syncthreads();
    float p[13];
    float sloc = 0.f;
    #pragma unroll
    for (int j = 0; j < 13; ++j) {
        p[j] = 0.f;
        if (eg + 8 * j < E1_) { p[j] = __expf(sc[j] - m); sloc += p[j]; }
    }
    red[l][eg] = sloc;
    __syncthreads();
    float ssum = 0.f;
    #pragma unroll
    for (int k = 0; k < 8; ++k) ssum += red[l][k];
    float inv = 1.f / ssum;
    bool valid = (l0 + l) < qn;
    if (valid) {
        float* row = &co_att[((size_t)b * L_ + l0 + l) * E1_];
        #pragma unroll
        for (int j = 0; j < 13; ++j) {
            int e = eg + 8 * j;
            if (e < E1_) row[e] = p[j] * inv;
        }
    }
    float maskv = valid ? inv : 0.f;
    #pragma unroll
    for (int j = 0; j < 13; ++j) {
        int e = eg + 8 * j;
        float v = (e < E1_) ? p[j] * maskv : 0.f;
        v += __shfl_xor(v, 1);  v += __shfl_xor(v, 2);
        v += __shfl_xor(v, 4);  v += __shfl_xor(v, 8);
        v += __shfl_xor(v, 16);
        if ((tid & 31) == 0 && e < E1_)
            partial[((size_t)b * NBLK3_ + mt) * E1_ + e] = v;
    }
}

// ---------------- K5: att[b,e] = min(sum of partials, 1)
__global__ __launch_bounds__(256) void k_final(const float* __restrict__ partial,
                                               float* __restrict__ att) {
    int i = blockIdx.x * 256 + threadIdx.x;
    if (i >= B_ * E_) return;
    int b = i / E_, e = i % E_;
    float s = 0.f;
    #pragma unroll
    for (int k = 0; k < NBLK3_; ++k) s += partial[((size_t)b * NBLK3_ + k) * E1_ + e];
    att[i] = fminf(s, 1.f);
}

extern "C" void kernel_launch(void* const* d_in, const int* in_sizes, int n_in,
                              void* d_out, int out_size, void* d_ws, size_t ws_size,
                              hipStream_t stream) {
    const float* q_enc    = (const float*)d_in[0];
    const float* hint     = (const float*)d_in[1];
    const float* W        = (const float*)d_in[2];
    const float* bias     = (const float*)d_in[3];
    const float* none_ent = (const float*)d_in[4];
    const int*   qlen     = (const int*)d_in[5];
    const int*   ranges   = (const int*)d_in[6];

    float* att    = (float*)d_out;
    float* co_att = att + (size_t)B_ * E_;

    u16* enc_hi = (u16*)d_ws;
    u16* enc_lo = enc_hi + (size_t)M2P_ * 1024;
    u16* w_hi   = enc_lo + (size_t)M2P_ * 1024;
    u16* w_lo   = w_hi + (size_t)1024 * 1024;
    u16* ep_hi  = w_lo + (size_t)1024 * 1024;
    u16* ep_lo  = ep_hi + (size_t)M2P_ * 1024;
    float* ep_last = (float*)(ep_lo + (size_t)M2P_ * 1024);
    float* part    = ep_last + M2P_;

    hipMemsetAsync(co_att, 0, (size_t)B_ * L_ * E1_ * sizeof(float), stream);

    k_encode<<<M2_, 256, 0, stream>>>(q_enc, none_ent, W, bias, ranges, enc_hi, enc_lo, ep_last);
    k_wsplit<<<1024, 256, 0, stream>>>(W, w_hi, w_lo);
    k_entproj<<<dim3(16, 51), 256, 0, stream>>>(enc_hi, enc_lo, w_hi, w_lo, bias, ep_hi, ep_lo);
    k_scores<<<dim3(NBLK3_, B_), 256, 0, stream>>>(q_enc, hint, ep_hi, ep_lo, ep_last, qlen, co_att, part);
    k_final<<<13, 256, 0, stream>>>(part, att);
}